// Round 10
// baseline (182.210 us; speedup 1.0000x reference)
//
#include <hip/hip_runtime.h>
#include <hip/hip_bf16.h>
#include <hip/hip_fp16.h>
#include <math.h>

// Problem constants
#define NPTS 65536
#define DIM  256
#define KC   512

// som_main geometry
#define BM    64                  // points per block
#define NBLK  (NPTS / BM)         // 1024 blocks
#define XSTR  264                 // x LDS row stride in halfs (528 B: 16B-aligned, bank-group shift 1)
#define EPS   0.01f               // exact-recheck margin (coarse err ~<2e-5)

// d_out layout (floats): [0]=loss, [1..1+16777216)=quantized, [16777217]=perplexity,
// [16777218..+65536)=enc_idx (as float)
#define QOFF  1
#define PIDX  16777217
#define EOFF  16777218

// d_ws layout:
//   wfh  _Float16[131072]  @ 0        (256 KB)  w hi, MFMA fragment order
//   wfl  _Float16[131072]  @ 262144   (256 KB)  w lo
//   wsq  float[512]        @ 524288
//   g    float[512]        @ 526336
//   hist int[512]          @ 528384
//   mse  double            @ 530432
// fragment order: off(c,k) = ((((c>>4)*8 + (k>>5))*4 + ((k>>3)&3))*128) + (c&15)*8 + (k&7)

typedef _Float16 h8    __attribute__((ext_vector_type(8)));
typedef float    f32x4 __attribute__((ext_vector_type(4)));

__device__ inline void cvt_split8(float4 a, float4 b, h8& hv, h8& lv) {
    float f[8] = {a.x, a.y, a.z, a.w, b.x, b.y, b.z, b.w};
    #pragma unroll
    for (int i = 0; i < 8; ++i) {
        _Float16 h = (_Float16)f[i];
        hv[i] = h;
        lv[i] = (_Float16)(f[i] - (float)h);
    }
}

// merge top-2 set with another top-2 set; first-index tie-break on best (r5-verified)
__device__ inline void merge_top2(float& b1, int& i1, float& b2, int& i2,
                                  float ob1, int oi1, float ob2, int oi2) {
    bool ow = (ob1 < b1) || (ob1 == b1 && oi1 < i1);
    float lb = ow ? b1 : ob1; int li = ow ? i1 : oi1;
    if (ow) { b1 = ob1; i1 = oi1; }
    float c2 = b2; int ci = i2;
    if (ob2 < c2 || (ob2 == c2 && oi2 < ci)) { c2 = ob2; ci = oi2; }
    if (lb  < c2 || (lb  == c2 && li  < ci)) { c2 = lb;  ci = li;  }
    b2 = c2; i2 = ci;
}

// exact fp32 distance (same accumulation family as the r3-passing kernel)
__device__ inline float exact_dist(const float* __restrict__ xr,
                                   const float* __restrict__ w, int c, float wsqc) {
    const float* wr = w + (size_t)c * DIM;
    float d0 = 0.f, d1 = 0.f, d2 = 0.f, d3 = 0.f;
    #pragma unroll 4
    for (int d = 0; d < DIM; d += 4) {
        d0 = fmaf(xr[d + 0], wr[d + 0], d0);
        d1 = fmaf(xr[d + 1], wr[d + 1], d1);
        d2 = fmaf(xr[d + 2], wr[d + 2], d2);
        d3 = fmaf(xr[d + 3], wr[d + 3], d3);
    }
    return wsqc - 2.f * ((d0 + d1) + (d2 + d3));
}

// ---------------- wsq: |w_k|^2 (exact r3 order) + zero hist/mse ----------------
__global__ __launch_bounds__(256) void som_wsq(const float* __restrict__ w,
                                               float* __restrict__ wsq,
                                               int* __restrict__ hist,
                                               double* __restrict__ mse_acc)
{
    int k = blockIdx.x * 256 + threadIdx.x;   // grid = 2
    const float4* r = reinterpret_cast<const float4*>(w + (size_t)k * DIM);
    float s0 = 0.f, s1 = 0.f, s2 = 0.f, s3 = 0.f;
    #pragma unroll 8
    for (int q = 0; q < DIM / 4; ++q) {
        float4 v = r[q];
        s0 = fmaf(v.x, v.x, s0);
        s1 = fmaf(v.y, v.y, s1);
        s2 = fmaf(v.z, v.z, s2);
        s3 = fmaf(v.w, v.w, s3);
    }
    wsq[k] = (s0 + s1) + (s2 + s3);
    hist[k] = 0;
    if (k == 0) *mse_acc = 0.0;
}

// ---------------- conv: split-f16 conversion of w into fragment order ----------------
__global__ __launch_bounds__(256) void som_conv(const float* __restrict__ w,
                                                _Float16* __restrict__ wfh,
                                                _Float16* __restrict__ wfl)
{
    const int tid = threadIdx.x;
    const int row = blockIdx.x * 8 + (tid >> 5);   // code row
    const int g   = tid & 31;                      // h8 unit within row
    const float4* r = reinterpret_cast<const float4*>(w + (size_t)row * DIM);
    float4 a = r[g * 2], b = r[g * 2 + 1];
    h8 hv, lv; cvt_split8(a, b, hv, lv);
    int dsl = g >> 2, kg = g & 3;
    int ctg = row >> 4, l15 = row & 15;
    size_t off = (((size_t)(ctg * 8 + dsl)) * 4 + kg) * 128 + l15 * 8;
    *reinterpret_cast<h8*>(wfh + off) = hv;
    *reinterpret_cast<h8*>(wfl + off) = lv;
}

// one dsl phase: 8 LDS B-reads + 48 MFMAs using preloaded A registers
#define MFMA_PHASE(dslv, AH, AL) do {                                                     \
    h8 Bh[4], Bl[4];                                                                      \
    _Pragma("unroll")                                                                     \
    for (int ct = 0; ct < 4; ++ct) {                                                      \
        int boff = (ct * 16 + l15) * XSTR + (dslv) * 32 + kg * 8;                         \
        Bh[ct] = *reinterpret_cast<const h8*>(&xh[boff]);                                 \
        Bl[ct] = *reinterpret_cast<const h8*>(&xl[boff]);                                 \
    }                                                                                     \
    _Pragma("unroll")                                                                     \
    for (int rt = 0; rt < 4; ++rt) {                                                      \
        _Pragma("unroll")                                                                 \
        for (int ct = 0; ct < 4; ++ct)                                                    \
            acc[rt][ct] = __builtin_amdgcn_mfma_f32_16x16x32_f16(AH[rt], Bh[ct], acc[rt][ct], 0, 0, 0); \
        _Pragma("unroll")                                                                 \
        for (int ct = 0; ct < 4; ++ct)                                                    \
            acc[rt][ct] = __builtin_amdgcn_mfma_f32_16x16x32_f16(AL[rt], Bh[ct], acc[rt][ct], 0, 0, 0); \
        _Pragma("unroll")                                                                 \
        for (int ct = 0; ct < 4; ++ct)                                                    \
            acc[rt][ct] = __builtin_amdgcn_mfma_f32_16x16x32_f16(AH[rt], Bl[ct], acc[rt][ct], 0, 0, 0); \
    }                                                                                     \
} while (0)

// ---------------- main: swapped-operand split-fp16 MFMA argmin ----------------
// 512 threads = 8 waves; wave wid owns codes [wid*64, wid*64+64).
// A-fragments (w) prefetched one dsl ahead in registers (ping-pong);
// mse via |x|^2 (accumulated during staging) + best_dist — no epilogue re-reads.
__global__ __launch_bounds__(512) void som_main(const float* __restrict__ x,
                                                const float* __restrict__ w,
                                                const _Float16* __restrict__ wfh,
                                                const _Float16* __restrict__ wfl,
                                                float* __restrict__ out,
                                                const float* __restrict__ wsq,
                                                int* __restrict__ hist,
                                                double* __restrict__ mse_acc)
{
    alignas(16) __shared__ _Float16 xh[BM * XSTR];   // 33,792 B
    alignas(16) __shared__ _Float16 xl[BM * XSTR];   // 33,792 B
    __shared__ float wsq_s[KC];                      // 2 KB
    __shared__ float xsq_s[BM];                      // 256 B
    __shared__ float red_b[8][BM], red_s[8][BM];     // 4 KB
    __shared__ int   red_ib[8][BM], red_is[8][BM];   // 4 KB

    const int tid  = threadIdx.x;
    const int lane = tid & 63;
    const int wid  = tid >> 6;        // wave 0..7: code group of 64
    const int l15  = lane & 15;       // point col / frag row
    const int kg   = lane >> 4;       // k-group 0..3
    const int ptBlock = blockIdx.x * BM;

    // ---- stage x tile: split to f16 hi/lo in LDS, accumulate |x|^2 on the fly ----
    const float4* xg4 = reinterpret_cast<const float4*>(x);
    #pragma unroll
    for (int it = 0; it < 4; ++it) {
        int u = it * 512 + tid;       // h8 unit: 64 rows x 32 groups
        int row = u >> 5, c8 = u & 31;
        float4 a = xg4[(size_t)(ptBlock + row) * 64 + c8 * 2];
        float4 b = xg4[(size_t)(ptBlock + row) * 64 + c8 * 2 + 1];
        h8 hv, lv; cvt_split8(a, b, hv, lv);
        *reinterpret_cast<h8*>(&xh[row * XSTR + c8 * 8]) = hv;
        *reinterpret_cast<h8*>(&xl[row * XSTR + c8 * 8]) = lv;
        // |x|^2 partial for this unit, reduce over the 32 lanes staging this row
        float s = ((fmaf(a.x, a.x, a.y * a.y) + fmaf(a.z, a.z, a.w * a.w))
                 + (fmaf(b.x, b.x, b.y * b.y) + fmaf(b.z, b.z, b.w * b.w)));
        #pragma unroll
        for (int m = 1; m <= 16; m <<= 1) s += __shfl_xor(s, m, 64);
        if ((lane & 31) == 0) xsq_s[row] = s;
    }
    wsq_s[tid] = wsq[tid];            // 512 threads cover K=512
    __syncthreads();                  // the only barrier before the merge

    const int codeBase = wid * 64;
    const int ctg0 = codeBase >> 4;   // first code-tile-group of this wave
    const int lane_off = kg * 128 + l15 * 8;
    const _Float16* __restrict__ pH = wfh + lane_off;
    const _Float16* __restrict__ pL = wfl + lane_off;

    f32x4 acc[4][4];                  // [rt (code tile)][ct (point tile)]
    #pragma unroll
    for (int rt = 0; rt < 4; ++rt)
        #pragma unroll
        for (int ct = 0; ct < 4; ++ct)
            acc[rt][ct] = (f32x4){0.f, 0.f, 0.f, 0.f};

    // A-register ping-pong: preload dsl=0
    h8 Ah0[4], Al0[4], Ah1[4], Al1[4];
    #pragma unroll
    for (int rt = 0; rt < 4; ++rt) {
        size_t off = ((size_t)((ctg0 + rt) * 8 + 0)) * 512;
        Ah0[rt] = *reinterpret_cast<const h8*>(pH + off);
        Al0[rt] = *reinterpret_cast<const h8*>(pL + off);
    }

    #pragma unroll 1
    for (int ds2 = 0; ds2 < 4; ++ds2) {
        const int dA = ds2 * 2, dB = dA + 1;
        // prefetch odd phase while even phase computes
        #pragma unroll
        for (int rt = 0; rt < 4; ++rt) {
            size_t off = ((size_t)((ctg0 + rt) * 8 + dB)) * 512;
            Ah1[rt] = *reinterpret_cast<const h8*>(pH + off);
            Al1[rt] = *reinterpret_cast<const h8*>(pL + off);
        }
        MFMA_PHASE(dA, Ah0, Al0);
        // prefetch next even phase while odd phase computes
        if (ds2 < 3) {
            #pragma unroll
            for (int rt = 0; rt < 4; ++rt) {
                size_t off = ((size_t)((ctg0 + rt) * 8 + dA + 2)) * 512;
                Ah0[rt] = *reinterpret_cast<const h8*>(pH + off);
                Al0[rt] = *reinterpret_cast<const h8*>(pL + off);
            }
        }
        MFMA_PHASE(dB, Ah1, Al1);
    }

    // per-lane top-2 state for point col = ct*16 + l15
    float sb[4], ss[4];
    int   ib[4], is2[4];
    #pragma unroll
    for (int ct = 0; ct < 4; ++ct) { sb[ct] = INFINITY; ss[ct] = INFINITY; ib[ct] = 0; is2[ct] = 0; }

    // in-lane top-2 scan, codes ascending in (rt, r)
    #pragma unroll
    for (int rt = 0; rt < 4; ++rt) {
        int cbase = codeBase + rt * 16 + kg * 4;
        #pragma unroll
        for (int ct = 0; ct < 4; ++ct) {
            #pragma unroll
            for (int r = 0; r < 4; ++r) {
                int c = cbase + r;
                float d = wsq_s[c] - 2.f * acc[rt][ct][r];
                if (d < sb[ct] || (d == sb[ct] && c < ib[ct])) {
                    ss[ct] = sb[ct]; is2[ct] = ib[ct]; sb[ct] = d; ib[ct] = c;
                } else if (d < ss[ct] || (d == ss[ct] && c < is2[ct])) {
                    ss[ct] = d; is2[ct] = c;
                }
            }
        }
    }

    // cross-lane merge over kg groups only: masks 16, 32
    #pragma unroll
    for (int ct = 0; ct < 4; ++ct) {
        #pragma unroll
        for (int m = 16; m <= 32; m <<= 1) {
            float ob1 = __shfl_xor(sb[ct], m, 64), ob2 = __shfl_xor(ss[ct], m, 64);
            int   oi1 = __shfl_xor(ib[ct], m, 64), oi2 = __shfl_xor(is2[ct], m, 64);
            merge_top2(sb[ct], ib[ct], ss[ct], is2[ct], ob1, oi1, ob2, oi2);
        }
    }
    if (kg == 0) {
        #pragma unroll
        for (int ct = 0; ct < 4; ++ct) {
            int p = ct * 16 + l15;
            red_b[wid][p] = sb[ct];  red_s[wid][p] = ss[ct];
            red_ib[wid][p] = ib[ct]; red_is[wid][p] = is2[ct];
        }
    }
    __syncthreads();

    // cross-wave merge + exact recheck + enc_idx + hist + mse (wave 0 only)
    if (tid < BM) {
        float b = red_b[0][tid], s = red_s[0][tid];
        int  bi = red_ib[0][tid], si = red_is[0][tid];
        #pragma unroll
        for (int g = 1; g < 8; ++g)
            merge_top2(b, bi, s, si, red_b[g][tid], red_ib[g][tid], red_s[g][tid], red_is[g][tid]);

        if (s - b < EPS) {            // near-tie: resolve in exact fp32 (rare)
            const float* xr = x + (size_t)(ptBlock + tid) * DIM;
            float d1 = exact_dist(xr, w, bi, wsq_s[bi]);
            float d2 = exact_dist(xr, w, si, wsq_s[si]);
            if (d2 < d1 || (d2 == d1 && si < bi)) { bi = si; b = d2; } else { b = d1; }
        }
        out[EOFF + ptBlock + tid] = (float)bi;
        atomicAdd(&hist[bi], 1);

        float msum = xsq_s[tid] + b;  // |x-w|^2 for this point (coarse err ~1e-4, mse-safe)
        #pragma unroll
        for (int m = 32; m; m >>= 1) msum += __shfl_xor(msum, m, 64);
        if (tid == 0) atomicAdd(mse_acc, (double)msum);
    }
}

// ---------------- quant: quantized[n] = w[enc_idx[n]] (gather + coalesced write) ----------------
// 4096 blocks x 256 threads; 16 rows per block, float4 lanes.
__global__ __launch_bounds__(256) void som_quant(const float* __restrict__ w,
                                                 float* __restrict__ out)
{
    const int tid = threadIdx.x;
    const int d4  = tid & 63;          // float4 column
    const int rg  = tid >> 6;          // row sub-group 0..3
    const float4* wg4 = reinterpret_cast<const float4*>(w);
    float4* q4 = reinterpret_cast<float4*>(out + QOFF);
    #pragma unroll
    for (int it = 0; it < 4; ++it) {
        int row = blockIdx.x * 16 + it * 4 + rg;
        int c = (int)out[EOFF + row];
        q4[(size_t)row * 64 + d4] = wg4[(size_t)c * 64 + d4];
    }
}

// ---------------- g[j] = sum_k bmat[j,k] * (wsq[k] + wsq[j] - 2 w_j.w_k) ----------------
__global__ __launch_bounds__(256) void som_g(const float* __restrict__ w,
                                             const float* __restrict__ bmat,
                                             const float* __restrict__ wsq,
                                             float* __restrict__ g)
{
    __shared__ float wj[DIM];
    __shared__ float psum[4];
    const int j = blockIdx.x;
    const int tid = threadIdx.x;
    wj[tid] = w[(size_t)j * DIM + tid];
    __syncthreads();
    const float wsqj = wsq[j];
    float sum = 0.f;
    for (int k = tid; k < KC; k += 256) {
        const float* wk = &w[(size_t)k * DIM];
        float d0 = 0.f, d1 = 0.f, d2 = 0.f, d3 = 0.f;
        #pragma unroll 4
        for (int d = 0; d < DIM; d += 4) {
            d0 = fmaf(wj[d + 0], wk[d + 0], d0);
            d1 = fmaf(wj[d + 1], wk[d + 1], d1);
            d2 = fmaf(wj[d + 2], wk[d + 2], d2);
            d3 = fmaf(wj[d + 3], wk[d + 3], d3);
        }
        float dot = (d0 + d1) + (d2 + d3);
        float t = wsq[k] + wsqj - 2.f * dot;
        sum = fmaf(bmat[(size_t)j * KC + k], t, sum);
    }
    #pragma unroll
    for (int m = 32; m; m >>= 1) sum += __shfl_xor(sum, m, 64);
    int lane = tid & 63, wid = tid >> 6;
    if (lane == 0) psum[wid] = sum;
    __syncthreads();
    if (tid == 0) g[j] = (psum[0] + psum[1]) + (psum[2] + psum[3]);
}

// ---------------- final: perplexity + loss ----------------
__global__ __launch_bounds__(512) void som_final(const int* __restrict__ hist,
                                                 const float* __restrict__ g,
                                                 const double* __restrict__ mse_acc,
                                                 float* __restrict__ out)
{
    __shared__ float e_part[8], k_part[8];
    const int tid = threadIdx.x;
    int cnt = hist[tid];
    float p = (float)cnt / (float)NPTS;
    float ent = -p * logf(p + 1e-10f);
    float koh = (float)cnt * g[tid];
    #pragma unroll
    for (int m = 32; m; m >>= 1) {
        ent += __shfl_xor(ent, m, 64);
        koh += __shfl_xor(koh, m, 64);
    }
    int lane = tid & 63, wid = tid >> 6;
    if (lane == 0) { e_part[wid] = ent; k_part[wid] = koh; }
    __syncthreads();
    if (tid == 0) {
        float es = 0.f, ks = 0.f;
        #pragma unroll
        for (int i = 0; i < 8; ++i) { es += e_part[i]; ks += k_part[i]; }
        float mse = (float)(*mse_acc / (double)(NPTS * (size_t)DIM));
        out[0] = fmaf(1.25f, mse, ks / (float)NPTS);
        out[PIDX] = expf(es);
    }
}

extern "C" void kernel_launch(void* const* d_in, const int* in_sizes, int n_in,
                              void* d_out, int out_size, void* d_ws, size_t ws_size,
                              hipStream_t stream) {
    const float* x    = (const float*)d_in[0];
    const float* w    = (const float*)d_in[1];
    const float* bmat = (const float*)d_in[2];
    float* out = (float*)d_out;

    _Float16* wfh = (_Float16*)d_ws;                         // 256 KB
    _Float16* wfl = wfh + 131072;                            // 256 KB
    float*  wsq  = (float*)((char*)d_ws + 524288);
    float*  g    = (float*)((char*)d_ws + 526336);
    int*    hist = (int*)((char*)d_ws + 528384);
    double* mse  = (double*)((char*)d_ws + 530432);

    som_wsq  <<<2, 256, 0, stream>>>(w, wsq, hist, mse);
    som_conv <<<64, 256, 0, stream>>>(w, wfh, wfl);
    som_main <<<NBLK, 512, 0, stream>>>(x, w, wfh, wfl, out, wsq, hist, mse);
    som_quant<<<4096, 256, 0, stream>>>(w, out);
    som_g    <<<KC, 256, 0, stream>>>(w, bmat, wsq, g);
    som_final<<<1, KC, 0, stream>>>(hist, g, mse, out);
}

// Round 11
// 182.128 us; speedup vs baseline: 1.0004x; 1.0004x over previous
//
#include <hip/hip_runtime.h>
#include <hip/hip_bf16.h>
#include <hip/hip_fp16.h>
#include <math.h>

// Problem constants
#define NPTS 65536
#define DIM  256
#define KC   512

// som_main geometry: persistent pipeline
#define BM    64                  // points per tile
#define NTILE 4                   // tiles per block
#define NBLK  256                 // 1 block per CU
#define XSTR  264                 // x LDS row stride in halfs (528 B, 16B-aligned)
#define EPS   0.01f               // exact-recheck margin (coarse err ~<2e-5)

// d_out layout (floats): [0]=loss, [1..1+16777216)=quantized, [16777217]=perplexity,
// [16777218..+65536)=enc_idx (as float)
#define QOFF  1
#define PIDX  16777217
#define EOFF  16777218

// d_ws layout:
//   wfh  _Float16[131072]  @ 0        (256 KB)  w hi, MFMA fragment order
//   wfl  _Float16[131072]  @ 262144   (256 KB)  w lo
//   wsq  float[512]        @ 524288
//   g    float[512]        @ 526336
//   hist int[512]          @ 528384
//   mse  double            @ 530432
// fragment order: off(c,k) = ((c>>4)*8 + (k>>5))*512 + ((k>>3)&3)*128 + (c&15)*8 + (k&7)

typedef _Float16 h8    __attribute__((ext_vector_type(8)));
typedef float    f32x4 __attribute__((ext_vector_type(4)));

__device__ inline void cvt_split8(float4 a, float4 b, h8& hv, h8& lv) {
    float f[8] = {a.x, a.y, a.z, a.w, b.x, b.y, b.z, b.w};
    #pragma unroll
    for (int i = 0; i < 8; ++i) {
        _Float16 h = (_Float16)f[i];
        hv[i] = h;
        lv[i] = (_Float16)(f[i] - (float)h);
    }
}

// merge top-2 set with another top-2 set; first-index tie-break on best (r5-verified)
__device__ inline void merge_top2(float& b1, int& i1, float& b2, int& i2,
                                  float ob1, int oi1, float ob2, int oi2) {
    bool ow = (ob1 < b1) || (ob1 == b1 && oi1 < i1);
    float lb = ow ? b1 : ob1; int li = ow ? i1 : oi1;
    if (ow) { b1 = ob1; i1 = oi1; }
    float c2 = b2; int ci = i2;
    if (ob2 < c2 || (ob2 == c2 && oi2 < ci)) { c2 = ob2; ci = oi2; }
    if (lb  < c2 || (lb  == c2 && li  < ci)) { c2 = lb;  ci = li;  }
    b2 = c2; i2 = ci;
}

// exact fp32 distance (same accumulation family as the r3-passing kernel)
__device__ inline float exact_dist(const float* __restrict__ xr,
                                   const float* __restrict__ w, int c, float wsqc) {
    const float* wr = w + (size_t)c * DIM;
    float d0 = 0.f, d1 = 0.f, d2 = 0.f, d3 = 0.f;
    #pragma unroll 4
    for (int d = 0; d < DIM; d += 4) {
        d0 = fmaf(xr[d + 0], wr[d + 0], d0);
        d1 = fmaf(xr[d + 1], wr[d + 1], d1);
        d2 = fmaf(xr[d + 2], wr[d + 2], d2);
        d3 = fmaf(xr[d + 3], wr[d + 3], d3);
    }
    return wsqc - 2.f * ((d0 + d1) + (d2 + d3));
}

// ---------------- wsq: |w_k|^2 (exact r3 order) + zero hist/mse ----------------
__global__ __launch_bounds__(256) void som_wsq(const float* __restrict__ w,
                                               float* __restrict__ wsq,
                                               int* __restrict__ hist,
                                               double* __restrict__ mse_acc)
{
    int k = blockIdx.x * 256 + threadIdx.x;   // grid = 2
    const float4* r = reinterpret_cast<const float4*>(w + (size_t)k * DIM);
    float s0 = 0.f, s1 = 0.f, s2 = 0.f, s3 = 0.f;
    #pragma unroll 8
    for (int q = 0; q < DIM / 4; ++q) {
        float4 v = r[q];
        s0 = fmaf(v.x, v.x, s0);
        s1 = fmaf(v.y, v.y, s1);
        s2 = fmaf(v.z, v.z, s2);
        s3 = fmaf(v.w, v.w, s3);
    }
    wsq[k] = (s0 + s1) + (s2 + s3);
    hist[k] = 0;
    if (k == 0) *mse_acc = 0.0;
}

// ---------------- conv: split-f16 conversion of w into fragment order ----------------
__global__ __launch_bounds__(256) void som_conv(const float* __restrict__ w,
                                                _Float16* __restrict__ wfh,
                                                _Float16* __restrict__ wfl)
{
    const int tid = threadIdx.x;
    const int row = blockIdx.x * 8 + (tid >> 5);   // code row
    const int g   = tid & 31;                      // h8 unit within row
    const float4* r = reinterpret_cast<const float4*>(w + (size_t)row * DIM);
    float4 a = r[g * 2], b = r[g * 2 + 1];
    h8 hv, lv; cvt_split8(a, b, hv, lv);
    int dsl = g >> 2, kg = g & 3;
    int ctg = row >> 4, l15 = row & 15;
    size_t off = (((size_t)(ctg * 8 + dsl)) * 4 + kg) * 128 + l15 * 8;
    *reinterpret_cast<h8*>(wfh + off) = hv;
    *reinterpret_cast<h8*>(wfl + off) = lv;
}

// ---------------- main: persistent, double-buffered, fused quantized write ----------------
// Grid 256 x 512 thr (8 waves). Block handles NTILE=4 point-tiles of 64.
// Pipeline per tile t: MFMA(buf[t&1]) -> B1 -> wave0 merge/outputs -> B1.5 ->
//   all: quant-write tile t, cvt+LDS-write tile t+1, issue x-loads tile t+2 -> B2.
__global__ __launch_bounds__(512) void som_main(const float* __restrict__ x,
                                                const float* __restrict__ w,
                                                const _Float16* __restrict__ wfh,
                                                const _Float16* __restrict__ wfl,
                                                float* __restrict__ out,
                                                const float* __restrict__ wsq,
                                                int* __restrict__ hist,
                                                double* __restrict__ mse_acc)
{
    alignas(16) __shared__ _Float16 xh[2][BM * XSTR];   // 2 x 33,792 B
    alignas(16) __shared__ _Float16 xl[2][BM * XSTR];   // 2 x 33,792 B
    __shared__ float wsq_s[KC];                         // 2 KB
    __shared__ float xsq_s[2][BM];                      // 512 B
    __shared__ float red_b[8][BM], red_s[8][BM];        // 4 KB
    __shared__ int   red_ib[8][BM], red_is[8][BM];      // 4 KB
    __shared__ int   bidx_s[BM];                        // 256 B

    const int tid  = threadIdx.x;
    const int lane = tid & 63;
    const int wid  = tid >> 6;        // wave 0..7: code group of 64
    const int l15  = lane & 15;
    const int kg   = lane >> 4;
    const int tile0 = blockIdx.x * NTILE;

    wsq_s[tid] = wsq[tid];            // 512 threads cover K=512

    const float4* xg4 = reinterpret_cast<const float4*>(x);
    const float4* wg4 = reinterpret_cast<const float4*>(w);
    float4* q4 = reinterpret_cast<float4*>(out + QOFF);

    float4 xr[4][2];                  // staged x regs (32 VGPRs), one tile in flight

    // ---- helpers (unrolled, static indexing) ----
    auto loadx = [&](int tt) {
        #pragma unroll
        for (int it = 0; it < 4; ++it) {
            int u = it * 512 + tid, row = u >> 5, c8 = u & 31;
            size_t base = (size_t)(tt * BM + row) * 64 + c8 * 2;
            xr[it][0] = xg4[base];
            xr[it][1] = xg4[base + 1];
        }
    };
    auto cvtwrite = [&](int c) {
        #pragma unroll
        for (int it = 0; it < 4; ++it) {
            int u = it * 512 + tid, row = u >> 5, c8 = u & 31;
            h8 hv, lv; cvt_split8(xr[it][0], xr[it][1], hv, lv);
            *reinterpret_cast<h8*>(&xh[c][row * XSTR + c8 * 8]) = hv;
            *reinterpret_cast<h8*>(&xl[c][row * XSTR + c8 * 8]) = lv;
            float4 a = xr[it][0], b = xr[it][1];
            float s = ((fmaf(a.x, a.x, a.y * a.y) + fmaf(a.z, a.z, a.w * a.w))
                     + (fmaf(b.x, b.x, b.y * b.y) + fmaf(b.z, b.z, b.w * b.w)));
            #pragma unroll
            for (int m = 1; m <= 16; m <<= 1) s += __shfl_xor(s, m, 64);
            if ((lane & 31) == 0) xsq_s[c][row] = s;
        }
    };

    // ---- prologue: stage tile 0, preload tile 1 ----
    loadx(tile0);
    cvtwrite(0);
    loadx(tile0 + 1);
    __syncthreads();

    const int codeBase = wid * 64;
    const int ctg0 = codeBase >> 4;
    const _Float16* __restrict__ pH = wfh + kg * 128 + l15 * 8;
    const _Float16* __restrict__ pL = wfl + kg * 128 + l15 * 8;

    #pragma unroll 1
    for (int t = 0; t < NTILE; ++t) {
        const int c = t & 1;
        const int ptBlock = (tile0 + t) * BM;
        const _Float16* __restrict__ bxh = xh[c];
        const _Float16* __restrict__ bxl = xl[c];

        f32x4 acc[4][4];
        #pragma unroll
        for (int rt = 0; rt < 4; ++rt)
            #pragma unroll
            for (int ct = 0; ct < 4; ++ct)
                acc[rt][ct] = (f32x4){0.f, 0.f, 0.f, 0.f};

        #pragma unroll 1
        for (int dsl = 0; dsl < 8; ++dsl) {
            h8 Bh[4], Bl[4];
            #pragma unroll
            for (int ct = 0; ct < 4; ++ct) {
                int boff = (ct * 16 + l15) * XSTR + dsl * 32 + kg * 8;
                Bh[ct] = *reinterpret_cast<const h8*>(&bxh[boff]);
                Bl[ct] = *reinterpret_cast<const h8*>(&bxl[boff]);
            }
            #pragma unroll
            for (int rt = 0; rt < 4; ++rt) {
                size_t aoff = ((size_t)((ctg0 + rt) * 8 + dsl)) * 512;
                h8 Ah = *reinterpret_cast<const h8*>(pH + aoff);
                h8 Al = *reinterpret_cast<const h8*>(pL + aoff);
                #pragma unroll
                for (int ct = 0; ct < 4; ++ct)
                    acc[rt][ct] = __builtin_amdgcn_mfma_f32_16x16x32_f16(Ah, Bh[ct], acc[rt][ct], 0, 0, 0);
                #pragma unroll
                for (int ct = 0; ct < 4; ++ct)
                    acc[rt][ct] = __builtin_amdgcn_mfma_f32_16x16x32_f16(Al, Bh[ct], acc[rt][ct], 0, 0, 0);
                #pragma unroll
                for (int ct = 0; ct < 4; ++ct)
                    acc[rt][ct] = __builtin_amdgcn_mfma_f32_16x16x32_f16(Ah, Bl[ct], acc[rt][ct], 0, 0, 0);
            }
        }

        // per-lane top-2 scan, codes ascending in (rt, r)
        float sb[4], ss[4];
        int   ib[4], is2[4];
        #pragma unroll
        for (int ct = 0; ct < 4; ++ct) { sb[ct] = INFINITY; ss[ct] = INFINITY; ib[ct] = 0; is2[ct] = 0; }
        #pragma unroll
        for (int rt = 0; rt < 4; ++rt) {
            int cbase = codeBase + rt * 16 + kg * 4;
            #pragma unroll
            for (int ct = 0; ct < 4; ++ct) {
                #pragma unroll
                for (int r = 0; r < 4; ++r) {
                    int cc = cbase + r;
                    float d = wsq_s[cc] - 2.f * acc[rt][ct][r];
                    if (d < sb[ct] || (d == sb[ct] && cc < ib[ct])) {
                        ss[ct] = sb[ct]; is2[ct] = ib[ct]; sb[ct] = d; ib[ct] = cc;
                    } else if (d < ss[ct] || (d == ss[ct] && cc < is2[ct])) {
                        ss[ct] = d; is2[ct] = cc;
                    }
                }
            }
        }
        // cross-lane merge over kg groups: masks 16, 32
        #pragma unroll
        for (int ct = 0; ct < 4; ++ct) {
            #pragma unroll
            for (int m = 16; m <= 32; m <<= 1) {
                float ob1 = __shfl_xor(sb[ct], m, 64), ob2 = __shfl_xor(ss[ct], m, 64);
                int   oi1 = __shfl_xor(ib[ct], m, 64), oi2 = __shfl_xor(is2[ct], m, 64);
                merge_top2(sb[ct], ib[ct], ss[ct], is2[ct], ob1, oi1, ob2, oi2);
            }
        }
        if (kg == 0) {
            #pragma unroll
            for (int ct = 0; ct < 4; ++ct) {
                int p = ct * 16 + l15;
                red_b[wid][p] = sb[ct];  red_s[wid][p] = ss[ct];
                red_ib[wid][p] = ib[ct]; red_is[wid][p] = is2[ct];
            }
        }
        __syncthreads();                            // B1: red ready, buf c consumed

        if (tid < BM) {
            float b = red_b[0][tid], s = red_s[0][tid];
            int  bi = red_ib[0][tid], si = red_is[0][tid];
            #pragma unroll
            for (int g = 1; g < 8; ++g)
                merge_top2(b, bi, s, si, red_b[g][tid], red_ib[g][tid], red_s[g][tid], red_is[g][tid]);

            if (s - b < EPS) {                      // near-tie: exact fp32 resolve (rare)
                const float* xrp = x + (size_t)(ptBlock + tid) * DIM;
                float d1 = exact_dist(xrp, w, bi, wsq_s[bi]);
                float d2 = exact_dist(xrp, w, si, wsq_s[si]);
                if (d2 < d1 || (d2 == d1 && si < bi)) { bi = si; b = d2; } else { b = d1; }
            }
            bidx_s[tid] = bi;
            out[EOFF + ptBlock + tid] = (float)bi;
            atomicAdd(&hist[bi], 1);

            float msum = xsq_s[c][tid] + b;         // |x-w|^2 (coarse err ~1e-4, mse-safe)
            #pragma unroll
            for (int m = 32; m; m >>= 1) msum += __shfl_xor(msum, m, 64);
            if (tid == 0) atomicAdd(mse_acc, (double)msum);
        }
        __syncthreads();                            // B1.5: bidx_s ready

        // fused quantized write: wave per row, 1 KB contiguous R/W
        #pragma unroll
        for (int r8 = 0; r8 < 8; ++r8) {
            int row = r8 * 8 + wid;
            int cc = bidx_s[row];
            q4[(size_t)(ptBlock + row) * 64 + lane] = wg4[(size_t)cc * 64 + lane];
        }
        // pipeline: stage tile t+1 into buf c^1; issue loads for tile t+2
        if (t + 1 < NTILE) cvtwrite(c ^ 1);
        if (t + 2 < NTILE) loadx(tile0 + t + 2);
        __syncthreads();                            // B2: buf c^1 ready
    }
}

// ---------------- g[j] = sum_k bmat[j,k] * (wsq[k] + wsq[j] - 2 w_j.w_k) ----------------
__global__ __launch_bounds__(256) void som_g(const float* __restrict__ w,
                                             const float* __restrict__ bmat,
                                             const float* __restrict__ wsq,
                                             float* __restrict__ g)
{
    __shared__ float wj[DIM];
    __shared__ float psum[4];
    const int j = blockIdx.x;
    const int tid = threadIdx.x;
    wj[tid] = w[(size_t)j * DIM + tid];
    __syncthreads();
    const float wsqj = wsq[j];
    float sum = 0.f;
    for (int k = tid; k < KC; k += 256) {
        const float* wk = &w[(size_t)k * DIM];
        float d0 = 0.f, d1 = 0.f, d2 = 0.f, d3 = 0.f;
        #pragma unroll 4
        for (int d = 0; d < DIM; d += 4) {
            d0 = fmaf(wj[d + 0], wk[d + 0], d0);
            d1 = fmaf(wj[d + 1], wk[d + 1], d1);
            d2 = fmaf(wj[d + 2], wk[d + 2], d2);
            d3 = fmaf(wj[d + 3], wk[d + 3], d3);
        }
        float dot = (d0 + d1) + (d2 + d3);
        float t = wsq[k] + wsqj - 2.f * dot;
        sum = fmaf(bmat[(size_t)j * KC + k], t, sum);
    }
    #pragma unroll
    for (int m = 32; m; m >>= 1) sum += __shfl_xor(sum, m, 64);
    int lane = tid & 63, wid = tid >> 6;
    if (lane == 0) psum[wid] = sum;
    __syncthreads();
    if (tid == 0) g[j] = (psum[0] + psum[1]) + (psum[2] + psum[3]);
}

// ---------------- final: perplexity + loss ----------------
__global__ __launch_bounds__(512) void som_final(const int* __restrict__ hist,
                                                 const float* __restrict__ g,
                                                 const double* __restrict__ mse_acc,
                                                 float* __restrict__ out)
{
    __shared__ float e_part[8], k_part[8];
    const int tid = threadIdx.x;
    int cnt = hist[tid];
    float p = (float)cnt / (float)NPTS;
    float ent = -p * logf(p + 1e-10f);
    float koh = (float)cnt * g[tid];
    #pragma unroll
    for (int m = 32; m; m >>= 1) {
        ent += __shfl_xor(ent, m, 64);
        koh += __shfl_xor(koh, m, 64);
    }
    int lane = tid & 63, wid = tid >> 6;
    if (lane == 0) { e_part[wid] = ent; k_part[wid] = koh; }
    __syncthreads();
    if (tid == 0) {
        float es = 0.f, ks = 0.f;
        #pragma unroll
        for (int i = 0; i < 8; ++i) { es += e_part[i]; ks += k_part[i]; }
        float mse = (float)(*mse_acc / (double)(NPTS * (size_t)DIM));
        out[0] = fmaf(1.25f, mse, ks / (float)NPTS);
        out[PIDX] = expf(es);
    }
}

extern "C" void kernel_launch(void* const* d_in, const int* in_sizes, int n_in,
                              void* d_out, int out_size, void* d_ws, size_t ws_size,
                              hipStream_t stream) {
    const float* x    = (const float*)d_in[0];
    const float* w    = (const float*)d_in[1];
    const float* bmat = (const float*)d_in[2];
    float* out = (float*)d_out;

    _Float16* wfh = (_Float16*)d_ws;                         // 256 KB
    _Float16* wfl = wfh + 131072;                            // 256 KB
    float*  wsq  = (float*)((char*)d_ws + 524288);
    float*  g    = (float*)((char*)d_ws + 526336);
    int*    hist = (int*)((char*)d_ws + 528384);
    double* mse  = (double*)((char*)d_ws + 530432);

    som_wsq  <<<2, 256, 0, stream>>>(w, wsq, hist, mse);
    som_conv <<<64, 256, 0, stream>>>(w, wfh, wfl);
    som_main <<<NBLK, 512, 0, stream>>>(x, w, wfh, wfl, out, wsq, hist, mse);
    som_g    <<<KC, 256, 0, stream>>>(w, bmat, wsq, g);
    som_final<<<1, KC, 0, stream>>>(hist, g, mse, out);
}